// Round 1
// baseline (9133.298 us; speedup 1.0000x reference)
//
// SingleDecoder (2-layer LSTM decoder) — persistent cooperative recurrence kernel.
//
// Pipeline:
//   zero_init -> pack_weights -> pack_xin -> pack_blob0/1
//   -> gemm pre1 = relu(xin@W1^T+b1)            [25600x256, K=576 padded]
//   -> gemm pre2 = relu(pre1@W2^T+b2)  (hi/lo bf16 split, [25600x512])
//   -> cooperative recurrence (256 blocks, 401 phases, custom grid barrier)
//   -> gemm out = H@Wo[:, :1024]^T + bo         [25600x552 fp32]
//
// Recurrence phase p: layer0 computes step t=p (K=1536: pre2hilo 512 + h0 1024),
// layer1 computes step t=p-1 (K=2048: h0 1024 + h1 1024). Weights live in the
// unified VGPR/AGPR file (4-way K-split per wave, 128 VGPRs of frags), cell
// state c in thread registers, gates cross-wave-reduced through LDS.
// h histories use fresh addresses per phase + agent-scope write-through stores,
// so plain loads are coherent cross-XCD with no cache invalidation needed.

#include <hip/hip_runtime.h>

typedef unsigned short u16;
typedef unsigned int   u32;
typedef short bf16x8 __attribute__((ext_vector_type(8)));
typedef float f32x4  __attribute__((ext_vector_type(4)));

#define SLOT   (64 * 1024)   // elements per h-history slot  [64 batch][1024]
#define PRE2S  (64 * 512)    // elements per pre2 slot       [64 batch][512 hi/lo]
#define GRID_R 256

// ---------------- workspace layout (bytes) ----------------
static constexpr size_t SZ_HIST   = 401ull * SLOT * 2;            // 52,559,872
static constexpr size_t OFF_H0    = 0;
static constexpr size_t OFF_H1    = OFF_H0 + SZ_HIST;
static constexpr size_t OFF_PRE2  = OFF_H1 + SZ_HIST;             // 25600*512*2
static constexpr size_t OFF_W1P   = OFF_PRE2 + 25600ull * 512 * 2;
static constexpr size_t OFF_W2B   = OFF_W1P + 256ull * 576 * 2;
static constexpr size_t OFF_WOB   = OFF_W2B + 256ull * 256 * 2;
static constexpr size_t OFF_B0    = OFF_WOB + 576ull * 1024 * 2;
static constexpr size_t OFF_B1    = OFF_B0 + 4096ull * 4;
static constexpr size_t OFF_BLOB0 = OFF_B1 + 4096ull * 4;         // 786432 chunks *16B
static constexpr size_t OFF_BLOB1 = OFF_BLOB0 + 786432ull * 16;   // 1048576 chunks *16B
static constexpr size_t OFF_BAR   = OFF_BLOB1 + 1048576ull * 16;
static constexpr size_t WS_NEED   = OFF_BAR + 256;                // ~162.3 MB

// ---------------- helpers ----------------
__device__ __forceinline__ u16 f2bf(float f) {
  u32 u = __builtin_bit_cast(u32, f);
  u32 r = (u + 0x7FFFu + ((u >> 16) & 1u)) >> 16;
  return (u16)r;
}
__device__ __forceinline__ float bf2f(u16 h) {
  u32 u = ((u32)h) << 16;
  return __builtin_bit_cast(float, u);
}
__device__ __forceinline__ float sigf(float x) { return 1.0f / (1.0f + __expf(-x)); }
__device__ __forceinline__ float tanh_fast(float x) {
  float e = __expf(-2.0f * fabsf(x));
  float t = (1.0f - e) / (1.0f + e);
  return (x >= 0.0f) ? t : -t;
}

// ---------------- setup kernels ----------------
__global__ void zero_init(const float* __restrict__ bih0, const float* __restrict__ bhh0,
                          const float* __restrict__ bih1, const float* __restrict__ bhh1,
                          u16* __restrict__ h0s, u16* __restrict__ h1s,
                          float* __restrict__ bias0, float* __restrict__ bias1,
                          u32* __restrict__ bar) {
  int idx = blockIdx.x * 256 + threadIdx.x;
  if (idx < 65536) { h0s[idx] = 0; h1s[idx] = 0; return; }
  idx -= 65536;
  if (idx < 4096) { bias0[idx] = bih0[idx] + bhh0[idx]; return; }
  idx -= 4096;
  if (idx < 4096) { bias1[idx] = bih1[idx] + bhh1[idx]; return; }
  idx -= 4096;
  if (idx < 16) bar[idx] = 0u;
}

__global__ void pack_weights(const float* __restrict__ W1, const float* __restrict__ W2,
                             const float* __restrict__ Wo,
                             u16* __restrict__ W1p, u16* __restrict__ W2b, u16* __restrict__ Wob) {
  int idx = blockIdx.x * 256 + threadIdx.x;
  if (idx < 147456) {  // W1p [256][576], pad K 552->576
    int n = idx / 576, k = idx % 576;
    W1p[idx] = f2bf(k < 552 ? W1[n * 552 + k] : 0.0f);
    return;
  }
  idx -= 147456;
  if (idx < 65536) { W2b[idx] = f2bf(W2[idx]); return; }  // [256][256]
  idx -= 65536;
  if (idx < 589824) {  // Wob [576][1024]: rows >=552 zero, cols = Wo[:, :1024]
    int n = idx >> 10, k = idx & 1023;
    Wob[idx] = f2bf(n < 552 ? Wo[n * 1152 + k] : 0.0f);
  }
}

__global__ void pack_xin(const float* __restrict__ S, u16* __restrict__ xin) {
  int idx = blockIdx.x * 256 + threadIdx.x;  // [25600][576]
  if (idx >= 25600 * 576) return;
  int m = idx / 576, d = idx % 576;
  int t = m >> 6, b = m & 63;
  float v = (t == 0 || d >= 552) ? 0.0f : S[(size_t)((t - 1) * 64 + b) * 552 + d];
  xin[idx] = f2bf(v);
}

// blob layout: chunk idx = (((b*4 + w)*S + s)*2 + mt)*64 + L, 8 bf16 per chunk.
// A-frag convention (16x16x32): value j of lane L = W[row = mt*16+(L&15)][k = KPW*w + 32*s + (L>>4)*8 + j]
__global__ void pack_blob0(const float* __restrict__ Wih0, const float* __restrict__ Whh0,
                           u16* __restrict__ blob) {
  int idx = blockIdx.x * 256 + threadIdx.x;   // 128*4*12*2*64 = 786432 chunks
  if (idx >= 786432) return;
  int L = idx & 63; int t = idx >> 6;
  int mt = t & 1; t >>= 1;
  int s = t % 12; t /= 12;
  int w = t & 3; int b = t >> 2;
  int rl = mt * 16 + (L & 15);
  int grow = (rl >> 3) * 1024 + b * 8 + (rl & 7);
  int kbase = w * 384 + s * 32 + (L >> 4) * 8;
  bf16x8 out;
#pragma unroll
  for (int j = 0; j < 8; ++j) {
    int k = kbase + j;
    float f = (k < 256) ? Wih0[(size_t)grow * 384 + k]
            : (k < 512) ? Wih0[(size_t)grow * 384 + (k - 256)]    // lo-split reuses same weights
                        : Whh0[(size_t)grow * 1024 + (k - 512)];
    out[j] = (short)f2bf(f);
  }
  *(bf16x8*)(blob + (size_t)idx * 8) = out;
}

__global__ void pack_blob1(const float* __restrict__ Wih1, const float* __restrict__ Whh1,
                           u16* __restrict__ blob) {
  int idx = blockIdx.x * 256 + threadIdx.x;   // 128*4*16*2*64 = 1048576 chunks
  if (idx >= 1048576) return;
  int L = idx & 63; int t = idx >> 6;
  int mt = t & 1; t >>= 1;
  int s = t & 15; t >>= 4;
  int w = t & 3; int b = t >> 2;
  int rl = mt * 16 + (L & 15);
  int grow = (rl >> 3) * 1024 + b * 8 + (rl & 7);
  int kbase = w * 512 + s * 32 + (L >> 4) * 8;
  bf16x8 out;
#pragma unroll
  for (int j = 0; j < 8; ++j) {
    int k = kbase + j;
    float f = (k < 1024) ? Wih1[(size_t)grow * 1024 + k]
                         : Whh1[(size_t)grow * 1024 + (k - 1024)];
    out[j] = (short)f2bf(f);
  }
  *(bf16x8*)(blob + (size_t)idx * 8) = out;
}

// ---------------- generic TN gemm: C[m][n] = sum_k A[m,k]*B[n,k] (+bias, relu) ----------------
// MODE 0: bf16 out; 1: fp32 out; 2: bf16 hi/lo out (cols n and 256+n, ldc=512)
template <bool RELU, int MODE>
__global__ __launch_bounds__(256) void gemm_tn(const u16* __restrict__ A, const u16* __restrict__ B,
                                               const float* __restrict__ bias, void* __restrict__ C,
                                               int K, int Nlim, int ldc) {
  const int tid = threadIdx.x;
  const int w = __builtin_amdgcn_readfirstlane(tid >> 6);
  const int L = tid & 63, u = L & 15, q = L >> 4;
  const int bx = blockIdx.x, by = blockIdx.y;
  const f32x4 fz = {0.f, 0.f, 0.f, 0.f};
  f32x4 acc[4] = {fz, fz, fz, fz};
  const int n = by * 64 + w * 16 + u;
  const u16* bp = B + (size_t)n * K + q * 8;
  const u16* ap = A + (size_t)(bx * 64 + u) * K + q * 8;
  for (int k0 = 0; k0 < K; k0 += 32) {
    bf16x8 bfr = *(const bf16x8*)(bp + k0);
#pragma unroll
    for (int mt = 0; mt < 4; ++mt) {
      bf16x8 afr = *(const bf16x8*)(ap + (size_t)mt * 16 * K + k0);
      acc[mt] = __builtin_amdgcn_mfma_f32_16x16x32_bf16(afr, bfr, acc[mt], 0, 0, 0);
    }
  }
  if (n < Nlim) {
    const float bvv = bias[n];
#pragma unroll
    for (int mt = 0; mt < 4; ++mt)
#pragma unroll
      for (int r = 0; r < 4; ++r) {
        const int m = bx * 64 + mt * 16 + q * 4 + r;   // C row=(L>>4)*4+reg, col=L&15 (verified layout)
        float v = acc[mt][r] + bvv;
        if (RELU) v = fmaxf(v, 0.0f);
        if (MODE == 1) {
          ((float*)C)[(size_t)m * ldc + n] = v;
        } else if (MODE == 0) {
          ((u16*)C)[(size_t)m * ldc + n] = f2bf(v);
        } else {
          u16 hi = f2bf(v);
          ((u16*)C)[(size_t)m * ldc + n] = hi;
          ((u16*)C)[(size_t)m * ldc + 256 + n] = f2bf(v - bf2f(hi));
        }
      }
  }
}

// ---------------- persistent recurrence ----------------
template <int LAYER, int S>
__device__ __forceinline__ void phase_loop(int cb, const u16* __restrict__ blob,
                                           const float* __restrict__ bias,
                                           const u16* __restrict__ pre2,
                                           u16* __restrict__ h0hist, u16* __restrict__ h1hist,
                                           u32* __restrict__ bar, float* __restrict__ red) {
  const int tid = threadIdx.x;
  const int w = __builtin_amdgcn_readfirstlane(tid >> 6);  // wave id = K-quarter
  const int L = tid & 63;
  const int u = L & 15;
  const int q = L >> 4;

  // resident weight fragments: wave's K-quarter of the block's 32 gate rows
  bf16x8 wf[S][2];
#pragma unroll
  for (int s = 0; s < S; ++s)
#pragma unroll
    for (int mt = 0; mt < 2; ++mt)
      wf[s][mt] = *(const bf16x8*)(blob + (size_t)(((((cb * 4 + w) * S + s) * 2 + mt) * 64 + L)) * 8);

  // cell-state mapping: thread -> (batch n_cell, local cols 2cp, 2cp+1)
  const int n_cell = tid & 63;
  const int cp = tid >> 6;
  float bv[4][2];
#pragma unroll
  for (int g = 0; g < 4; ++g) {
    bv[g][0] = bias[g * 1024 + cb * 8 + 2 * cp];
    bv[g][1] = bias[g * 1024 + cb * 8 + 2 * cp + 1];
  }
  float cst0 = 0.0f, cst1 = 0.0f;

  const int lane512 = u * 512 + q * 8;
  const int lane1024 = u * 1024 + q * 8;
  const int KPW = S * 32;
  const int KSEG = (LAYER == 0) ? 512 : 1024;
  const f32x4 fz = {0.f, 0.f, 0.f, 0.f};

  for (int p = 0; p <= 400; ++p) {
    const bool active = (LAYER == 0) ? (p < 400) : (p >= 1);
    if (active) {
      const u16* seg0;
      const u16* seg1;
      if (LAYER == 0) {
        seg0 = pre2 + (size_t)p * PRE2S;          // [64][512] hi/lo
        seg1 = h0hist + (size_t)p * SLOT;         // h0[t-1]
      } else {
        seg0 = h0hist + (size_t)p * SLOT;         // h0[t]   (t = p-1)
        seg1 = h1hist + (size_t)(p - 1) * SLOT;   // h1[t-1]
      }
      f32x4 acc[2][4];
#pragma unroll
      for (int mt = 0; mt < 2; ++mt)
#pragma unroll
        for (int nt = 0; nt < 4; ++nt) acc[mt][nt] = fz;

#pragma unroll
      for (int s = 0; s < S; ++s) {
        const int kg = w * KPW + s * 32;
        const u16* base;
        int l_off, nstep, ko;
        if (kg < KSEG) {
          base = seg0; ko = kg;
          l_off = (LAYER == 0) ? lane512 : lane1024;
          nstep = (LAYER == 0) ? (16 * 512) : (16 * 1024);
        } else {
          base = seg1; ko = kg - KSEG;
          l_off = lane1024; nstep = 16 * 1024;
        }
        const u16* lp = base + l_off + ko;
        bf16x8 hfr[4];
#pragma unroll
        for (int nt = 0; nt < 4; ++nt) hfr[nt] = *(const bf16x8*)(lp + nt * nstep);
#pragma unroll
        for (int mt = 0; mt < 2; ++mt)
#pragma unroll
          for (int nt = 0; nt < 4; ++nt)
            acc[mt][nt] = __builtin_amdgcn_mfma_f32_16x16x32_bf16(wf[s][mt], hfr[nt], acc[mt][nt], 0, 0, 0);
      }
      // spill partials for cross-wave K-reduction (row pad 65 avoids bank conflicts)
#pragma unroll
      for (int mt = 0; mt < 2; ++mt)
#pragma unroll
        for (int nt = 0; nt < 4; ++nt)
#pragma unroll
          for (int r = 0; r < 4; ++r)
            red[((w * 32) + mt * 16 + q * 4 + r) * 65 + nt * 16 + u] = acc[mt][nt][r];
    }
    __syncthreads();
    if (active) {
      float g4[4][2];
#pragma unroll
      for (int g = 0; g < 4; ++g)
#pragma unroll
        for (int cc = 0; cc < 2; ++cc) {
          const int row = g * 8 + 2 * cp + cc;
          g4[g][cc] = red[(0 * 32 + row) * 65 + n_cell] + red[(1 * 32 + row) * 65 + n_cell] +
                      red[(2 * 32 + row) * 65 + n_cell] + red[(3 * 32 + row) * 65 + n_cell] + bv[g][cc];
        }
      u32 hpack;
      {
        float ig = sigf(g4[0][0]), fg = sigf(g4[1][0]), gg = tanh_fast(g4[2][0]), og = sigf(g4[3][0]);
        float cn = fg * cst0 + ig * gg; cst0 = cn;
        hpack = (u32)f2bf(og * tanh_fast(cn));
      }
      {
        float ig = sigf(g4[0][1]), fg = sigf(g4[1][1]), gg = tanh_fast(g4[2][1]), og = sigf(g4[3][1]);
        float cn = fg * cst1 + ig * gg; cst1 = cn;
        hpack |= ((u32)f2bf(og * tanh_fast(cn))) << 16;
      }
      u16* dst = (LAYER == 0) ? (h0hist + (size_t)(p + 1) * SLOT) : (h1hist + (size_t)p * SLOT);
      u32* dp = (u32*)(dst + n_cell * 1024 + cb * 8 + 2 * cp);
      // agent-scope write-through: visible at LLC so cross-XCD plain loads (fresh addr) see it
      __hip_atomic_store(dp, hpack, __ATOMIC_RELAXED, __HIP_MEMORY_SCOPE_AGENT);
    }
    __syncthreads();  // drains all waves' h stores (vmcnt(0) before s_barrier)
    if (p < 400) {
      if (tid == 0) {
        __hip_atomic_fetch_add(bar, 1u, __ATOMIC_RELEASE, __HIP_MEMORY_SCOPE_AGENT);
        const u32 target = (u32)(p + 1) * GRID_R;
        int guard = 0;
        while (__hip_atomic_load(bar, __ATOMIC_RELAXED, __HIP_MEMORY_SCOPE_AGENT) < target) {
          __builtin_amdgcn_s_sleep(1);
          if (++guard > (1 << 20)) break;  // bounded: fail visibly instead of hanging
        }
      }
      __syncthreads();
    }
  }
}

__global__ __launch_bounds__(256, 1) void decoder_recurrence(
    const u16* __restrict__ blob0, const u16* __restrict__ blob1,
    const float* __restrict__ bias0, const float* __restrict__ bias1,
    const u16* __restrict__ pre2, u16* __restrict__ h0hist, u16* __restrict__ h1hist,
    u32* __restrict__ bar) {
  __shared__ float red[4 * 32 * 65];
  const int bid = blockIdx.x;
  const int cb = bid & 127;
  if (bid < 128)
    phase_loop<0, 12>(cb, blob0, bias0, pre2, h0hist, h1hist, bar, red);
  else
    phase_loop<1, 16>(cb, blob1, bias1, pre2, h0hist, h1hist, bar, red);
}

// ---------------- host launcher ----------------
extern "C" void kernel_launch(void* const* d_in, const int* in_sizes, int n_in,
                              void* d_out, int out_size, void* d_ws, size_t ws_size,
                              hipStream_t stream) {
  (void)in_sizes; (void)n_in; (void)out_size;
  if (ws_size < WS_NEED) return;  // visible clean failure rather than OOB writes

  const float* S    = (const float*)d_in[0];
  const float* W1   = (const float*)d_in[1];
  const float* b1   = (const float*)d_in[2];
  const float* W2   = (const float*)d_in[3];
  const float* b2   = (const float*)d_in[4];
  const float* Wih0 = (const float*)d_in[5];
  const float* Whh0 = (const float*)d_in[6];
  const float* bih0 = (const float*)d_in[7];
  const float* bhh0 = (const float*)d_in[8];
  const float* Wih1 = (const float*)d_in[9];
  const float* Whh1 = (const float*)d_in[10];
  const float* bih1 = (const float*)d_in[11];
  const float* bhh1 = (const float*)d_in[12];
  const float* Wo   = (const float*)d_in[13];
  const float* bo   = (const float*)d_in[14];

  char* ws = (char*)d_ws;
  u16* h0hist = (u16*)(ws + OFF_H0);
  u16* h1hist = (u16*)(ws + OFF_H1);
  u16* pre2   = (u16*)(ws + OFF_PRE2);
  u16* W1p    = (u16*)(ws + OFF_W1P);
  u16* W2b    = (u16*)(ws + OFF_W2B);
  u16* Wob    = (u16*)(ws + OFF_WOB);
  float* bias0 = (float*)(ws + OFF_B0);
  float* bias1 = (float*)(ws + OFF_B1);
  u16* blob0  = (u16*)(ws + OFF_BLOB0);
  u16* blob1  = (u16*)(ws + OFF_BLOB1);
  u32* bar    = (u32*)(ws + OFF_BAR);
  // aliases into hist slots 1.. (dead before the recurrence writes them)
  u16* xin  = (u16*)(ws + OFF_H0 + 131072);  // [25600][576]
  u16* pre1 = (u16*)(ws + OFF_H1 + 131072);  // [25600][256]

  zero_init<<<289, 256, 0, stream>>>(bih0, bhh0, bih1, bhh1, h0hist, h1hist, bias0, bias1, bar);
  pack_weights<<<3136, 256, 0, stream>>>(W1, W2, Wo, W1p, W2b, Wob);
  pack_xin<<<57600, 256, 0, stream>>>(S, xin);
  pack_blob0<<<3072, 256, 0, stream>>>(Wih0, Whh0, blob0);
  pack_blob1<<<4096, 256, 0, stream>>>(Wih1, Whh1, blob1);

  gemm_tn<true, 0><<<dim3(400, 4), 256, 0, stream>>>(xin, W1p, b1, pre1, 576, 256, 256);
  gemm_tn<true, 2><<<dim3(400, 4), 256, 0, stream>>>(pre1, W2b, b2, pre2, 256, 256, 512);

  const u16* a0 = blob0; const u16* a1 = blob1;
  const float* a2 = bias0; const float* a3 = bias1;
  const u16* a4 = pre2; u16* a5 = h0hist; u16* a6 = h1hist; u32* a7 = bar;
  void* kargs[] = {&a0, &a1, &a2, &a3, &a4, &a5, &a6, &a7};
  hipLaunchCooperativeKernel((void*)decoder_recurrence, dim3(GRID_R), dim3(256), kargs, 0, stream);

  gemm_tn<false, 1><<<dim3(400, 9), 256, 0, stream>>>(h1hist + SLOT, Wob, bo, (float*)d_out, 1024, 552, 552);
}

// Round 2
// 6524.922 us; speedup vs baseline: 1.3998x; 1.3998x over previous
//
// SingleDecoder (2-layer LSTM decoder) — persistent cooperative recurrence kernel.
//
// Round 2: barrier restructure. Round-1 counters showed 21.5us/phase with
// MfmaUtil 3.5%, HBM 2% -> ~18us/phase was the single-counter global barrier
// (256 serialized same-line LLC RMWs + 256 pollers). This round:
//   - two independent 128-block barrier domains (layer0 / layer1)
//   - layer1 consumes layer0 via monotone watermark rel0 (layer0 free-runs ahead)
//   - tree barrier per domain: 8 arrival lines x 16 blocks -> root -> release word
// Datapath (verified correct, absmax 6.1e-5) unchanged.

#include <hip/hip_runtime.h>

typedef unsigned short u16;
typedef unsigned int   u32;
typedef short bf16x8 __attribute__((ext_vector_type(8)));
typedef float f32x4  __attribute__((ext_vector_type(4)));

#define SLOT   (64 * 1024)   // elements per h-history slot  [64 batch][1024]
#define PRE2S  (64 * 512)    // elements per pre2 slot       [64 batch][512 hi/lo]
#define GRID_R 256

// ---------------- workspace layout (bytes) ----------------
static constexpr size_t SZ_HIST   = 401ull * SLOT * 2;            // 52,559,872
static constexpr size_t OFF_H0    = 0;
static constexpr size_t OFF_H1    = OFF_H0 + SZ_HIST;
static constexpr size_t OFF_PRE2  = OFF_H1 + SZ_HIST;             // 25600*512*2
static constexpr size_t OFF_W1P   = OFF_PRE2 + 25600ull * 512 * 2;
static constexpr size_t OFF_W2B   = OFF_W1P + 256ull * 576 * 2;
static constexpr size_t OFF_WOB   = OFF_W2B + 256ull * 256 * 2;
static constexpr size_t OFF_B0    = OFF_WOB + 576ull * 1024 * 2;
static constexpr size_t OFF_B1    = OFF_B0 + 4096ull * 4;
static constexpr size_t OFF_BLOB0 = OFF_B1 + 4096ull * 4;         // 786432 chunks *16B
static constexpr size_t OFF_BLOB1 = OFF_BLOB0 + 786432ull * 16;   // 1048576 chunks *16B
static constexpr size_t OFF_BAR   = OFF_BLOB1 + 1048576ull * 16;
static constexpr size_t WS_NEED   = OFF_BAR + 4096;               // ~162.3 MB

// barrier region layout (u32 words, 64B lines = 16 words):
//   domain base: layer0 = word 0, layer1 = word 512
//   arr lines: words (g<<4), g=0..7   root: word 128   release: word 144

// ---------------- helpers ----------------
__device__ __forceinline__ u16 f2bf(float f) {
  u32 u = __builtin_bit_cast(u32, f);
  u32 r = (u + 0x7FFFu + ((u >> 16) & 1u)) >> 16;
  return (u16)r;
}
__device__ __forceinline__ float bf2f(u16 h) {
  u32 u = ((u32)h) << 16;
  return __builtin_bit_cast(float, u);
}
__device__ __forceinline__ float sigf(float x) { return 1.0f / (1.0f + __expf(-x)); }
__device__ __forceinline__ float tanh_fast(float x) {
  float e = __expf(-2.0f * fabsf(x));
  float t = (1.0f - e) / (1.0f + e);
  return (x >= 0.0f) ? t : -t;
}

// ---------------- setup kernels ----------------
__global__ void zero_init(const float* __restrict__ bih0, const float* __restrict__ bhh0,
                          const float* __restrict__ bih1, const float* __restrict__ bhh1,
                          u16* __restrict__ h0s, u16* __restrict__ h1s,
                          float* __restrict__ bias0, float* __restrict__ bias1,
                          u32* __restrict__ bar) {
  int idx = blockIdx.x * 256 + threadIdx.x;
  if (idx < 65536) { h0s[idx] = 0; h1s[idx] = 0; return; }
  idx -= 65536;
  if (idx < 4096) { bias0[idx] = bih0[idx] + bhh0[idx]; return; }
  idx -= 4096;
  if (idx < 4096) { bias1[idx] = bih1[idx] + bhh1[idx]; return; }
  idx -= 4096;
  if (idx < 1024) bar[idx] = 0u;
}

__global__ void pack_weights(const float* __restrict__ W1, const float* __restrict__ W2,
                             const float* __restrict__ Wo,
                             u16* __restrict__ W1p, u16* __restrict__ W2b, u16* __restrict__ Wob) {
  int idx = blockIdx.x * 256 + threadIdx.x;
  if (idx < 147456) {  // W1p [256][576], pad K 552->576
    int n = idx / 576, k = idx % 576;
    W1p[idx] = f2bf(k < 552 ? W1[n * 552 + k] : 0.0f);
    return;
  }
  idx -= 147456;
  if (idx < 65536) { W2b[idx] = f2bf(W2[idx]); return; }  // [256][256]
  idx -= 65536;
  if (idx < 589824) {  // Wob [576][1024]: rows >=552 zero, cols = Wo[:, :1024]
    int n = idx >> 10, k = idx & 1023;
    Wob[idx] = f2bf(n < 552 ? Wo[n * 1152 + k] : 0.0f);
  }
}

__global__ void pack_xin(const float* __restrict__ S, u16* __restrict__ xin) {
  int idx = blockIdx.x * 256 + threadIdx.x;  // [25600][576]
  if (idx >= 25600 * 576) return;
  int m = idx / 576, d = idx % 576;
  int t = m >> 6, b = m & 63;
  float v = (t == 0 || d >= 552) ? 0.0f : S[(size_t)((t - 1) * 64 + b) * 552 + d];
  xin[idx] = f2bf(v);
}

// blob layout: chunk idx = (((b*4 + w)*S + s)*2 + mt)*64 + L, 8 bf16 per chunk.
// A-frag convention (16x16x32): value j of lane L = W[row = mt*16+(L&15)][k = KPW*w + 32*s + (L>>4)*8 + j]
__global__ void pack_blob0(const float* __restrict__ Wih0, const float* __restrict__ Whh0,
                           u16* __restrict__ blob) {
  int idx = blockIdx.x * 256 + threadIdx.x;   // 128*4*12*2*64 = 786432 chunks
  if (idx >= 786432) return;
  int L = idx & 63; int t = idx >> 6;
  int mt = t & 1; t >>= 1;
  int s = t % 12; t /= 12;
  int w = t & 3; int b = t >> 2;
  int rl = mt * 16 + (L & 15);
  int grow = (rl >> 3) * 1024 + b * 8 + (rl & 7);
  int kbase = w * 384 + s * 32 + (L >> 4) * 8;
  bf16x8 out;
#pragma unroll
  for (int j = 0; j < 8; ++j) {
    int k = kbase + j;
    float f = (k < 256) ? Wih0[(size_t)grow * 384 + k]
            : (k < 512) ? Wih0[(size_t)grow * 384 + (k - 256)]    // lo-split reuses same weights
                        : Whh0[(size_t)grow * 1024 + (k - 512)];
    out[j] = (short)f2bf(f);
  }
  *(bf16x8*)(blob + (size_t)idx * 8) = out;
}

__global__ void pack_blob1(const float* __restrict__ Wih1, const float* __restrict__ Whh1,
                           u16* __restrict__ blob) {
  int idx = blockIdx.x * 256 + threadIdx.x;   // 128*4*16*2*64 = 1048576 chunks
  if (idx >= 1048576) return;
  int L = idx & 63; int t = idx >> 6;
  int mt = t & 1; t >>= 1;
  int s = t & 15; t >>= 4;
  int w = t & 3; int b = t >> 2;
  int rl = mt * 16 + (L & 15);
  int grow = (rl >> 3) * 1024 + b * 8 + (rl & 7);
  int kbase = w * 512 + s * 32 + (L >> 4) * 8;
  bf16x8 out;
#pragma unroll
  for (int j = 0; j < 8; ++j) {
    int k = kbase + j;
    float f = (k < 1024) ? Wih1[(size_t)grow * 1024 + k]
                         : Whh1[(size_t)grow * 1024 + (k - 1024)];
    out[j] = (short)f2bf(f);
  }
  *(bf16x8*)(blob + (size_t)idx * 8) = out;
}

// ---------------- generic TN gemm: C[m][n] = sum_k A[m,k]*B[n,k] (+bias, relu) ----------------
// MODE 0: bf16 out; 1: fp32 out; 2: bf16 hi/lo out (cols n and 256+n, ldc=512)
template <bool RELU, int MODE>
__global__ __launch_bounds__(256) void gemm_tn(const u16* __restrict__ A, const u16* __restrict__ B,
                                               const float* __restrict__ bias, void* __restrict__ C,
                                               int K, int Nlim, int ldc) {
  const int tid = threadIdx.x;
  const int w = __builtin_amdgcn_readfirstlane(tid >> 6);
  const int L = tid & 63, u = L & 15, q = L >> 4;
  const int bx = blockIdx.x, by = blockIdx.y;
  const f32x4 fz = {0.f, 0.f, 0.f, 0.f};
  f32x4 acc[4] = {fz, fz, fz, fz};
  const int n = by * 64 + w * 16 + u;
  const u16* bp = B + (size_t)n * K + q * 8;
  const u16* ap = A + (size_t)(bx * 64 + u) * K + q * 8;
  for (int k0 = 0; k0 < K; k0 += 32) {
    bf16x8 bfr = *(const bf16x8*)(bp + k0);
#pragma unroll
    for (int mt = 0; mt < 4; ++mt) {
      bf16x8 afr = *(const bf16x8*)(ap + (size_t)mt * 16 * K + k0);
      acc[mt] = __builtin_amdgcn_mfma_f32_16x16x32_bf16(afr, bfr, acc[mt], 0, 0, 0);
    }
  }
  if (n < Nlim) {
    const float bvv = bias[n];
#pragma unroll
    for (int mt = 0; mt < 4; ++mt)
#pragma unroll
      for (int r = 0; r < 4; ++r) {
        const int m = bx * 64 + mt * 16 + q * 4 + r;   // C row=(L>>4)*4+reg, col=L&15 (verified layout)
        float v = acc[mt][r] + bvv;
        if (RELU) v = fmaxf(v, 0.0f);
        if (MODE == 1) {
          ((float*)C)[(size_t)m * ldc + n] = v;
        } else if (MODE == 0) {
          ((u16*)C)[(size_t)m * ldc + n] = f2bf(v);
        } else {
          u16 hi = f2bf(v);
          ((u16*)C)[(size_t)m * ldc + n] = hi;
          ((u16*)C)[(size_t)m * ldc + 256 + n] = f2bf(v - bf2f(hi));
        }
      }
  }
}

// ---------------- persistent recurrence ----------------
// LAYER 0: phase p computes h0[t=p]: reads pre2[p] (K 0..511 hi/lo) + h0 slot p, writes h0 slot p+1.
// LAYER 1: phase p computes h1[t=p]: reads h0 slot p+1 (watermark rel0 >= p+1) + h1 slot p,
//          writes h1 slot p+1.
template <int LAYER, int S>
__device__ __forceinline__ void phase_loop(int cb, const u16* __restrict__ blob,
                                           const float* __restrict__ bias,
                                           const u16* __restrict__ pre2,
                                           u16* __restrict__ h0hist, u16* __restrict__ h1hist,
                                           u32* __restrict__ bar, float* __restrict__ red) {
  const int tid = threadIdx.x;
  const int w = __builtin_amdgcn_readfirstlane(tid >> 6);  // wave id = K-quarter
  const int L = tid & 63;
  const int u = L & 15;
  const int q = L >> 4;

  // resident weight fragments: wave's K-quarter of the block's 32 gate rows
  bf16x8 wf[S][2];
#pragma unroll
  for (int s = 0; s < S; ++s)
#pragma unroll
    for (int mt = 0; mt < 2; ++mt)
      wf[s][mt] = *(const bf16x8*)(blob + (size_t)(((((cb * 4 + w) * S + s) * 2 + mt) * 64 + L)) * 8);

  // cell-state mapping: thread -> (batch n_cell, local cols 2cp, 2cp+1)
  const int n_cell = tid & 63;
  const int cp = tid >> 6;
  float bv[4][2];
#pragma unroll
  for (int g = 0; g < 4; ++g) {
    bv[g][0] = bias[g * 1024 + cb * 8 + 2 * cp];
    bv[g][1] = bias[g * 1024 + cb * 8 + 2 * cp + 1];
  }
  float cst0 = 0.0f, cst1 = 0.0f;

  const int lane512 = u * 512 + q * 8;
  const int lane1024 = u * 1024 + q * 8;
  const int KPW = S * 32;
  const int KSEG = (LAYER == 0) ? 512 : 1024;
  const f32x4 fz = {0.f, 0.f, 0.f, 0.f};

  // barrier lines (64B-spaced): arr[g]=word g<<4, root=word 128, release=word 144
  u32* const dom   = bar + (LAYER ? 512 : 0);
  u32* const arrp  = dom + ((cb >> 4) << 4);
  u32* const rootp = dom + 128;
  u32* const relp  = dom + 144;
  u32* const rel0p = bar + 144;

  // layer1 phase 0 needs h0 slot 1 (layer0 phase 0 done)
  if (LAYER == 1 && tid == 0) {
    int guard = 0;
    while (__hip_atomic_load(rel0p, __ATOMIC_RELAXED, __HIP_MEMORY_SCOPE_AGENT) < 1u) {
      __builtin_amdgcn_s_sleep(2);
      if (++guard > (1 << 20)) break;
    }
  }
  __syncthreads();

  for (int p = 0; p < 400; ++p) {
    const u16* seg0;
    const u16* seg1;
    if (LAYER == 0) {
      seg0 = pre2 + (size_t)p * PRE2S;            // [64][512] hi/lo
      seg1 = h0hist + (size_t)p * SLOT;           // h0[t-1]
    } else {
      seg0 = h0hist + (size_t)(p + 1) * SLOT;     // h0[t]
      seg1 = h1hist + (size_t)p * SLOT;           // h1[t-1]
    }
    f32x4 acc[2][4];
#pragma unroll
    for (int mt = 0; mt < 2; ++mt)
#pragma unroll
      for (int nt = 0; nt < 4; ++nt) acc[mt][nt] = fz;

#pragma unroll
    for (int s = 0; s < S; ++s) {
      const int kg = w * KPW + s * 32;
      const u16* base;
      int l_off, nstep, ko;
      if (kg < KSEG) {
        base = seg0; ko = kg;
        l_off = (LAYER == 0) ? lane512 : lane1024;
        nstep = (LAYER == 0) ? (16 * 512) : (16 * 1024);
      } else {
        base = seg1; ko = kg - KSEG;
        l_off = lane1024; nstep = 16 * 1024;
      }
      const u16* lp = base + l_off + ko;
      bf16x8 hfr[4];
#pragma unroll
      for (int nt = 0; nt < 4; ++nt) hfr[nt] = *(const bf16x8*)(lp + nt * nstep);
#pragma unroll
      for (int mt = 0; mt < 2; ++mt)
#pragma unroll
        for (int nt = 0; nt < 4; ++nt)
          acc[mt][nt] = __builtin_amdgcn_mfma_f32_16x16x32_bf16(wf[s][mt], hfr[nt], acc[mt][nt], 0, 0, 0);
    }
    // spill partials for cross-wave K-reduction (row pad 65 avoids bank conflicts)
#pragma unroll
    for (int mt = 0; mt < 2; ++mt)
#pragma unroll
      for (int nt = 0; nt < 4; ++nt)
#pragma unroll
        for (int r = 0; r < 4; ++r)
          red[((w * 32) + mt * 16 + q * 4 + r) * 65 + nt * 16 + u] = acc[mt][nt][r];
    __syncthreads();
    {
      float g4[4][2];
#pragma unroll
      for (int g = 0; g < 4; ++g)
#pragma unroll
        for (int cc = 0; cc < 2; ++cc) {
          const int row = g * 8 + 2 * cp + cc;
          g4[g][cc] = red[(0 * 32 + row) * 65 + n_cell] + red[(1 * 32 + row) * 65 + n_cell] +
                      red[(2 * 32 + row) * 65 + n_cell] + red[(3 * 32 + row) * 65 + n_cell] + bv[g][cc];
        }
      u32 hpack;
      {
        float ig = sigf(g4[0][0]), fg = sigf(g4[1][0]), gg = tanh_fast(g4[2][0]), og = sigf(g4[3][0]);
        float cn = fg * cst0 + ig * gg; cst0 = cn;
        hpack = (u32)f2bf(og * tanh_fast(cn));
      }
      {
        float ig = sigf(g4[0][1]), fg = sigf(g4[1][1]), gg = tanh_fast(g4[2][1]), og = sigf(g4[3][1]);
        float cn = fg * cst1 + ig * gg; cst1 = cn;
        hpack |= ((u32)f2bf(og * tanh_fast(cn))) << 16;
      }
      u16* dst = (LAYER == 0) ? (h0hist + (size_t)(p + 1) * SLOT) : (h1hist + (size_t)(p + 1) * SLOT);
      u32* dp = (u32*)(dst + n_cell * 1024 + cb * 8 + 2 * cp);
      // agent-scope write-through: visible at LLC so cross-XCD plain loads (fresh addr) see it
      __hip_atomic_store(dp, hpack, __ATOMIC_RELAXED, __HIP_MEMORY_SCOPE_AGENT);
    }
    __syncthreads();  // drains ALL waves' h stores (each wave: vmcnt(0) before s_barrier)
    if (LAYER == 0 || p + 1 < 400) {   // layer1's final write has no in-kernel consumer
      if (tid == 0) {
        u32 old = __hip_atomic_fetch_add(arrp, 1u, __ATOMIC_RELEASE, __HIP_MEMORY_SCOPE_AGENT);
        if (old == (u32)(16 * (p + 1) - 1)) {       // last of my 16-block group this phase
          u32 o2 = __hip_atomic_fetch_add(rootp, 1u, __ATOMIC_RELEASE, __HIP_MEMORY_SCOPE_AGENT);
          if (o2 == (u32)(8 * (p + 1) - 1))          // last group leader this phase
            __hip_atomic_store(relp, (u32)(p + 1), __ATOMIC_RELEASE, __HIP_MEMORY_SCOPE_AGENT);
        }
        int guard = 0;
        while (__hip_atomic_load(relp, __ATOMIC_RELAXED, __HIP_MEMORY_SCOPE_AGENT) < (u32)(p + 1)) {
          __builtin_amdgcn_s_sleep(2);
          if (++guard > (1 << 20)) break;  // bounded: fail visibly instead of hanging
        }
        if (LAYER == 1 && p + 1 < 400) {
          // watermark for next phase: h0 slot p+2 ready (layer0 free-runs ahead, usually no wait)
          guard = 0;
          while (__hip_atomic_load(rel0p, __ATOMIC_RELAXED, __HIP_MEMORY_SCOPE_AGENT) < (u32)(p + 2)) {
            __builtin_amdgcn_s_sleep(2);
            if (++guard > (1 << 20)) break;
          }
        }
      }
      __syncthreads();
    }
  }
}

__global__ __launch_bounds__(256, 1) void decoder_recurrence(
    const u16* __restrict__ blob0, const u16* __restrict__ blob1,
    const float* __restrict__ bias0, const float* __restrict__ bias1,
    const u16* __restrict__ pre2, u16* __restrict__ h0hist, u16* __restrict__ h1hist,
    u32* __restrict__ bar) {
  __shared__ float red[4 * 32 * 65];
  const int bid = blockIdx.x;
  const int cb = bid & 127;
  if (bid < 128)
    phase_loop<0, 12>(cb, blob0, bias0, pre2, h0hist, h1hist, bar, red);
  else
    phase_loop<1, 16>(cb, blob1, bias1, pre2, h0hist, h1hist, bar, red);
}

// ---------------- host launcher ----------------
extern "C" void kernel_launch(void* const* d_in, const int* in_sizes, int n_in,
                              void* d_out, int out_size, void* d_ws, size_t ws_size,
                              hipStream_t stream) {
  (void)in_sizes; (void)n_in; (void)out_size;
  if (ws_size < WS_NEED) return;  // visible clean failure rather than OOB writes

  const float* S    = (const float*)d_in[0];
  const float* W1   = (const float*)d_in[1];
  const float* b1   = (const float*)d_in[2];
  const float* W2   = (const float*)d_in[3];
  const float* b2   = (const float*)d_in[4];
  const float* Wih0 = (const float*)d_in[5];
  const float* Whh0 = (const float*)d_in[6];
  const float* bih0 = (const float*)d_in[7];
  const float* bhh0 = (const float*)d_in[8];
  const float* Wih1 = (const float*)d_in[9];
  const float* Whh1 = (const float*)d_in[10];
  const float* bih1 = (const float*)d_in[11];
  const float* bhh1 = (const float*)d_in[12];
  const float* Wo   = (const float*)d_in[13];
  const float* bo   = (const float*)d_in[14];

  char* ws = (char*)d_ws;
  u16* h0hist = (u16*)(ws + OFF_H0);
  u16* h1hist = (u16*)(ws + OFF_H1);
  u16* pre2   = (u16*)(ws + OFF_PRE2);
  u16* W1p    = (u16*)(ws + OFF_W1P);
  u16* W2b    = (u16*)(ws + OFF_W2B);
  u16* Wob    = (u16*)(ws + OFF_WOB);
  float* bias0 = (float*)(ws + OFF_B0);
  float* bias1 = (float*)(ws + OFF_B1);
  u16* blob0  = (u16*)(ws + OFF_BLOB0);
  u16* blob1  = (u16*)(ws + OFF_BLOB1);
  u32* bar    = (u32*)(ws + OFF_BAR);
  // aliases into hist slots 1.. (dead before the recurrence writes them)
  u16* xin  = (u16*)(ws + OFF_H0 + 131072);  // [25600][576]
  u16* pre1 = (u16*)(ws + OFF_H1 + 131072);  // [25600][256]

  zero_init<<<292, 256, 0, stream>>>(bih0, bhh0, bih1, bhh1, h0hist, h1hist, bias0, bias1, bar);
  pack_weights<<<3136, 256, 0, stream>>>(W1, W2, Wo, W1p, W2b, Wob);
  pack_xin<<<57600, 256, 0, stream>>>(S, xin);
  pack_blob0<<<3072, 256, 0, stream>>>(Wih0, Whh0, blob0);
  pack_blob1<<<4096, 256, 0, stream>>>(Wih1, Whh1, blob1);

  gemm_tn<true, 0><<<dim3(400, 4), 256, 0, stream>>>(xin, W1p, b1, pre1, 576, 256, 256);
  gemm_tn<true, 2><<<dim3(400, 4), 256, 0, stream>>>(pre1, W2b, b2, pre2, 256, 256, 512);

  const u16* a0 = blob0; const u16* a1 = blob1;
  const float* a2 = bias0; const float* a3 = bias1;
  const u16* a4 = pre2; u16* a5 = h0hist; u16* a6 = h1hist; u32* a7 = bar;
  void* kargs[] = {&a0, &a1, &a2, &a3, &a4, &a5, &a6, &a7};
  hipLaunchCooperativeKernel((void*)decoder_recurrence, dim3(GRID_R), dim3(256), kargs, 0, stream);

  gemm_tn<false, 1><<<dim3(400, 9), 256, 0, stream>>>(h1hist + SLOT, Wob, bo, (float*)d_out, 1024, 552, 552);
}